// Round 8
// baseline (666.206 us; speedup 1.0000x reference)
//
#include <hip/hip_runtime.h>

// ---------------------------------------------------------------------------
// FastRCNN head: RoIPool + FC(25088->4096) + FC(4096->4096) + heads (21/84).
// R8 = R7 + B register pipeline deepened to 4 slots (3-iter prefetch slack).
// R7 diagnosis: iter_time ~= exposed B-load latency (slack was 1 iter);
// latency-bound at ~20% HBM. Deeper slack -> iter_time = latency/3.
// Everything else (BN=128 tile, layouts, barrier scheme) R7-validated.
// ---------------------------------------------------------------------------

typedef __attribute__((ext_vector_type(8))) __bf16 bf16x8;
typedef __attribute__((ext_vector_type(4))) float f32x4;
typedef __attribute__((ext_vector_type(4))) unsigned int u32x4;

#define N_ROIS 512
#define FH 50
#define FW 50
#define KK1 25088      // 512*49
#define D1 4096

#define BM 512
#define BN 128
#define BK 32

// ---------------------------------------------------------------------------
// RoIPool: block = (roi, channel-group of 64). 4096 blocks (validated R5-R7).
// ---------------------------------------------------------------------------
__global__ __launch_bounds__(256) void roipool_kernel(
    const float* __restrict__ x, const float* __restrict__ rois,
    __bf16* __restrict__ pooled) {
  const int bid = blockIdx.x;
  const int roi = bid >> 3;
  const int cg = bid & 7;
  const float s = 0.0625f;
  const float r0 = rois[roi * 4 + 0], r1 = rois[roi * 4 + 1];
  const float r2 = rois[roi * 4 + 2], r3 = rois[roi * 4 + 3];
  int x1 = (int)(r0 * s); x1 = min(max(x1, 0), FW - 1);
  int y1 = (int)(r1 * s); y1 = min(max(y1, 0), FH - 1);
  int x2 = (int)(r2 * s); x2 = min(max(x2, 0), FW - 1);
  int y2 = (int)(r3 * s); y2 = min(max(y2, 0), FH - 1);
  const int ww = x2 - x1 + 1, hh = y2 - y1 + 1;
  __shared__ int cs[7], ce[7], rs[7], re[7];
  if (threadIdx.x < 7) {
    int i = threadIdx.x;
    cs[i] = x1 + (i * ww) / 7;
    ce[i] = x1 + ((i + 1) * ww + 6) / 7;
    rs[i] = y1 + (i * hh) / 7;
    re[i] = y1 + ((i + 1) * hh + 6) / 7;
  }
  __syncthreads();
  for (int idx = threadIdx.x; idx < 64 * 49; idx += 256) {
    int cl = idx / 49;
    int p = idx - cl * 49;
    int py = p / 7, px = p - py * 7;
    const int c = cg * 64 + cl;
    const float* base = x + (size_t)c * (FH * FW);
    float m = -3.402823466e38f;
    for (int y = rs[py]; y < re[py]; ++y) {
      const float* rowp = base + y * FW;
      for (int xx = cs[px]; xx < ce[px]; ++xx) m = fmaxf(m, rowp[xx]);
    }
    pooled[(size_t)roi * KK1 + c * 49 + p] = (__bf16)m;
  }
}

// ---------------------------------------------------------------------------
// GEMM: part[z][512][npad] = A[512,K](bf16) @ B[K,N](fp32 -> bf16 at stage)
// z = bid & ((1<<zshift)-1) (XCD-pins K-windows), n0 = (bid>>zshift)*128.
// Wave tile 64x128; acc[4][8]; A reg ping-pong (1-iter slack, L2-resident);
// B reg pipeline 4-deep: iter it: LOAD_B(it+4)->slot[it%4], after barrier
// WRITE_B tile it+1 from slot[(it+1)%4], MFMA consumes LDS tile it.
// LDS Bu 2 x 8KB, layout/swizzle R5/R7-validated.
// Sync: lgkmcnt(0) + raw s_barrier once per iter; no vmcnt(0) drain.
// ---------------------------------------------------------------------------
template <typename OutT>
__global__ __launch_bounds__(512, 2) void gemm_kernel(
    const __bf16* __restrict__ A, const float* __restrict__ B,
    OutT* __restrict__ part, int N, int K, int kslice, int npad, int zshift) {
  __shared__ unsigned int Bu[2][2048];  // 2 x 8KB
  const int tid = threadIdx.x;
  const int lane = tid & 63;
  const int w = tid >> 6;
  const int bid = blockIdx.x;
  const int z = bid & ((1 << zshift) - 1);
  const int n0 = (bid >> zshift) * BN;
  const int kbeg = z * kslice;
  const int niters = kslice / BK;  // 98, 16, or 2 -> always even
  const bool fullN = (n0 + BN) <= N;

  const int fr = lane & 15;
  const int ks = lane >> 4;

  f32x4 acc[4][8];
#pragma unroll
  for (int i = 0; i < 4; ++i)
#pragma unroll
    for (int j = 0; j < 8; ++j) acc[i][j] = (f32x4){0.f, 0.f, 0.f, 0.f};

  const int kmax = kbeg + kslice;

  // B staging: thread -> k-octet + single column (R7-validated)
  const int bc = tid & 127;       // column 0..127
  const int bkq = tid >> 7;       // k-octet 0..3
  const int bidx = bc * 16 + ((bkq ^ ((bc >> 2) & 3)) << 2);  // 16B aligned

  // static register state (rule #20)
  bf16x8 afA0, afA1, afA2, afA3, afB0, afB1, afB2, afB3;
  float bA0, bA1, bA2, bA3, bA4, bA5, bA6, bA7;
  float bB0, bB1, bB2, bB3, bB4, bB5, bB6, bB7;
  float bC0, bC1, bC2, bC3, bC4, bC5, bC6, bC7;
  float bD0, bD1, bD2, bD3, bD4, bD5, bD6, bD7;

#define LOAD_A(d0, d1, d2, d3, t)                                   \
  {                                                                 \
    int kk = kbeg + (t) * BK;                                       \
    if (kk >= kmax) kk = kbeg; /* clamped dup, never consumed */    \
    const __bf16* ap = A + (size_t)(w * 64 + fr) * K + kk + ks * 8; \
    d0 = *(const bf16x8*)(ap);                                      \
    d1 = *(const bf16x8*)(ap + (size_t)16 * K);                     \
    d2 = *(const bf16x8*)(ap + (size_t)32 * K);                     \
    d3 = *(const bf16x8*)(ap + (size_t)48 * K);                     \
  }

#define LOAD_B(S, t)                                           \
  {                                                            \
    int kg = kbeg + (t) * BK;                                  \
    if (kg >= kmax) kg = kbeg; /* clamped dup */               \
    const float* g0 = B + (size_t)(kg + 8 * bkq) * N;          \
    const int cc = n0 + bc;                                    \
    if (fullN) {                                               \
      S##0 = g0[cc];                S##1 = g0[(size_t)N + cc];     \
      S##2 = g0[(size_t)2 * N + cc]; S##3 = g0[(size_t)3 * N + cc];\
      S##4 = g0[(size_t)4 * N + cc]; S##5 = g0[(size_t)5 * N + cc];\
      S##6 = g0[(size_t)6 * N + cc]; S##7 = g0[(size_t)7 * N + cc];\
    } else {                                                   \
      const bool ok = cc < N;                                  \
      S##0 = ok ? g0[cc] : 0.f;                                \
      S##1 = ok ? g0[(size_t)N + cc] : 0.f;                    \
      S##2 = ok ? g0[(size_t)2 * N + cc] : 0.f;                \
      S##3 = ok ? g0[(size_t)3 * N + cc] : 0.f;                \
      S##4 = ok ? g0[(size_t)4 * N + cc] : 0.f;                \
      S##5 = ok ? g0[(size_t)5 * N + cc] : 0.f;                \
      S##6 = ok ? g0[(size_t)6 * N + cc] : 0.f;                \
      S##7 = ok ? g0[(size_t)7 * N + cc] : 0.f;                \
    }                                                          \
  }

#define WRITE_B(buf, S)                                        \
  {                                                            \
    union { __bf16 h[2]; unsigned int u; } q0, q1, q2, q3;     \
    q0.h[0] = (__bf16)S##0; q0.h[1] = (__bf16)S##1;            \
    q1.h[0] = (__bf16)S##2; q1.h[1] = (__bf16)S##3;            \
    q2.h[0] = (__bf16)S##4; q2.h[1] = (__bf16)S##5;            \
    q3.h[0] = (__bf16)S##6; q3.h[1] = (__bf16)S##7;            \
    *(u32x4*)&Bu[buf][bidx] = (u32x4){q0.u, q1.u, q2.u, q3.u}; \
  }

  // prologue: A(0); B tiles 0..3 in flight (slots A..D); tile 0 -> LDS
  LOAD_A(afA0, afA1, afA2, afA3, 0);
  LOAD_B(bA, 0);
  LOAD_B(bB, 1);
  LOAD_B(bC, 2);
  LOAD_B(bD, 3);
  WRITE_B(0, bA);

  // iter it: LOAD_A(it+1) [alt slot], LOAD_B(it+4)->slot[it%4],
  //          lgkmcnt(0)+barrier, WRITE_B(tile it+1 from slot[(it+1)%4]),
  //          MFMA on Bu[it&1].
#define BODY(it, pA0, pA1, pA2, pA3, nA0, nA1, nA2, nA3, ldB, wrB)    \
  {                                                                   \
    LOAD_A(nA0, nA1, nA2, nA3, (it) + 1);                             \
    LOAD_B(ldB, (it) + 4);                                            \
    asm volatile("s_waitcnt lgkmcnt(0)" ::: "memory");                \
    __builtin_amdgcn_s_barrier();                                     \
    __builtin_amdgcn_sched_barrier(0);                                \
    if ((it) + 1 < niters) WRITE_B(((it) + 1) & 1, wrB);              \
    _Pragma("unroll")                                                 \
    for (int nf = 0; nf < 8; ++nf) {                                  \
      const int c = nf * 16 + fr;                                     \
      const int slot = ks ^ ((c >> 2) & 3);                           \
      bf16x8 bfr = *(const bf16x8*)((const char*)&Bu[(it) & 1][0] +   \
                                    c * 64 + slot * 16);              \
      acc[0][nf] = __builtin_amdgcn_mfma_f32_16x16x32_bf16(pA0, bfr, acc[0][nf], 0, 0, 0); \
      acc[1][nf] = __builtin_amdgcn_mfma_f32_16x16x32_bf16(pA1, bfr, acc[1][nf], 0, 0, 0); \
      acc[2][nf] = __builtin_amdgcn_mfma_f32_16x16x32_bf16(pA2, bfr, acc[2][nf], 0, 0, 0); \
      acc[3][nf] = __builtin_amdgcn_mfma_f32_16x16x32_bf16(pA3, bfr, acc[3][nf], 0, 0, 0); \
    }                                                                 \
  }

  int it = 0;
  for (; it + 3 < niters; it += 4) {
    BODY(it + 0, afA0, afA1, afA2, afA3, afB0, afB1, afB2, afB3, bA, bB);
    BODY(it + 1, afB0, afB1, afB2, afB3, afA0, afA1, afA2, afA3, bB, bC);
    BODY(it + 2, afA0, afA1, afA2, afA3, afB0, afB1, afB2, afB3, bC, bD);
    BODY(it + 3, afB0, afB1, afB2, afB3, afA0, afA1, afA2, afA3, bD, bA);
  }
  if (it < niters) {  // niters % 4 == 2 tail (98, 2)
    BODY(it + 0, afA0, afA1, afA2, afA3, afB0, afB1, afB2, afB3, bA, bB);
    BODY(it + 1, afB0, afB1, afB2, afB3, afA0, afA1, afA2, afA3, bB, bC);
  }
#undef BODY
#undef WRITE_B
#undef LOAD_B
#undef LOAD_A

  // epilogue: C/D layout col = lane&15, row = (lane>>4)*4 + r
  const int r0 = ks * 4;
  OutT* pbase = part + (size_t)z * 512 * npad;
#pragma unroll
  for (int mf = 0; mf < 4; ++mf)
#pragma unroll
    for (int nf = 0; nf < 8; ++nf) {
      const int col = n0 + nf * 16 + fr;
#pragma unroll
      for (int r = 0; r < 4; ++r) {
        const int row = w * 64 + mf * 16 + r0 + r;
        pbase[(size_t)row * npad + col] = (OutT)acc[mf][nf][r];
      }
    }
}

// sum bf16 split-K partials + bias, relu -> bf16 activations [512][4096]
__global__ __launch_bounds__(256) void reduce_relu_kernel(
    const __bf16* __restrict__ part, const float* __restrict__ bias,
    __bf16* __restrict__ out, int nsplit) {
  const int idx = blockIdx.x * 256 + threadIdx.x;
  const int flat = idx * 8;
  if (flat >= 512 * 4096) return;
  float s[8];
#pragma unroll
  for (int j = 0; j < 8; ++j) s[j] = 0.f;
  for (int sp = 0; sp < nsplit; ++sp) {
    bf16x8 v = *(const bf16x8*)(part + (size_t)sp * (512 * 4096) + flat);
#pragma unroll
    for (int j = 0; j < 8; ++j) s[j] += (float)v[j];
  }
  const int nb = flat & 4095;
  bf16x8 o;
#pragma unroll
  for (int j = 0; j < 8; ++j) {
    float v = s[j] + bias[nb + j];
    o[j] = (__bf16)(v > 0.f ? v : 0.f);
  }
  *(bf16x8*)(out + flat) = o;
}

// final: sum split-K fp32 partials (stride 128) + bias -> d_out fp32
__global__ __launch_bounds__(256) void reduce_out_kernel(
    const float* __restrict__ pc, const float* __restrict__ pr,
    const float* __restrict__ bcls, const float* __restrict__ breg,
    float* __restrict__ out, int nsplit) {
  const int gid = blockIdx.x * 256 + threadIdx.x;
  if (gid >= 512 * 105) return;
  if (gid < 512 * 21) {
    const int m = gid / 21, j = gid - m * 21;
    float s = bcls[j];
    for (int sp = 0; sp < nsplit; ++sp)
      s += pc[(size_t)sp * 512 * 128 + m * 128 + j];
    out[gid] = s;
  } else {
    const int g = gid - 512 * 21;
    const int m = g / 84, j = g - m * 84;
    float s = breg[j];
    for (int sp = 0; sp < nsplit; ++sp)
      s += pr[(size_t)sp * 512 * 128 + m * 128 + j];
    out[gid] = s;
  }
}

extern "C" void kernel_launch(void* const* d_in, const int* in_sizes, int n_in,
                              void* d_out, int out_size, void* d_ws, size_t ws_size,
                              hipStream_t stream) {
  (void)in_sizes; (void)n_in; (void)out_size;
  const float* x    = (const float*)d_in[0];
  const float* rois = (const float*)d_in[2];
  const float* W1   = (const float*)d_in[3];
  const float* b1   = (const float*)d_in[4];
  const float* W2   = (const float*)d_in[5];
  const float* b2   = (const float*)d_in[6];
  const float* Wcls = (const float*)d_in[7];
  const float* bcls = (const float*)d_in[8];
  const float* Wreg = (const float*)d_in[9];
  const float* breg = (const float*)d_in[10];
  float* out = (float*)d_out;

  const size_t pooled_b = (size_t)512 * KK1 * 2;        // 25,690,112
  const size_t act_b = (size_t)512 * D1 * 2;            // 4 MiB
  const size_t need8 = pooled_b + (size_t)8 * act_b + 2 * act_b;
  const int ns = (ws_size >= need8) ? 8 : 2;            // ws ~1.6GB: ns=8
  const int zshift = (ns == 8) ? 3 : 1;

  char* ws = (char*)d_ws;
  __bf16* pooled = (__bf16*)ws;
  __bf16* part1 = (__bf16*)(ws + pooled_b);             // ns * 4MiB
  __bf16* f1 = (__bf16*)(ws + pooled_b + (size_t)ns * act_b);
  __bf16* f2 = (__bf16*)(ws + pooled_b + (size_t)ns * act_b + act_b);
  __bf16* part2 = (__bf16*)ws;                          // alias dead pooled+part1
  float* pcls = (float*)ws;                             // heads phase aliases
  float* preg = (float*)(ws + (size_t)64 * 512 * 128 * 4);  // +16.8MB

  // 1) RoIPool -> pooled bf16 [512, 25088]; 4096 blocks for occupancy
  roipool_kernel<<<N_ROIS * 8, 256, 0, stream>>>(x, rois, pooled);

  // 2) GEMM1: pooled @ W1[25088,4096]; W1 read exactly once; z-pinned XCDs
  gemm_kernel<__bf16><<<32 * ns, 512, 0, stream>>>(
      pooled, W1, part1, 4096, KK1, KK1 / ns, 4096, zshift);
  reduce_relu_kernel<<<1024, 256, 0, stream>>>(part1, b1, f1, ns);

  // 3) GEMM2: f1 @ W2[4096,4096]
  gemm_kernel<__bf16><<<32 * ns, 512, 0, stream>>>(
      f1, W2, part2, 4096, 4096, 4096 / ns, 4096, zshift);
  reduce_relu_kernel<<<1024, 256, 0, stream>>>(part2, b2, f2, ns);

  // 4) heads: single n-tile each (21,84 <= 128), split-K=64, npad=128
  gemm_kernel<float><<<64, 512, 0, stream>>>(
      f2, Wcls, pcls, 21, 4096, 64, 128, 6);
  gemm_kernel<float><<<64, 512, 0, stream>>>(
      f2, Wreg, preg, 84, 4096, 64, 128, 6);
  reduce_out_kernel<<<(512 * 105 + 255) / 256, 256, 0, stream>>>(
      pcls, preg, bcls, breg, out, 64);
}

// Round 9
// 418.709 us; speedup vs baseline: 1.5911x; 1.5911x over previous
//
#include <hip/hip_runtime.h>

// ---------------------------------------------------------------------------
// FastRCNN head: RoIPool + FC(25088->4096) + FC(4096->4096) + heads (21/84).
// R9: R7 structure with B pipeline = 3 reg slots (2-iter slack, unroll-by-3),
// single-set A loads (R6: prefetch null; saves 16 VGPR), launch_bounds(512,1)
// (R8's (512,2) capped VGPR at 128 -> 441MB scratch spill, the regression).
// ---------------------------------------------------------------------------

typedef __attribute__((ext_vector_type(8))) __bf16 bf16x8;
typedef __attribute__((ext_vector_type(4))) float f32x4;
typedef __attribute__((ext_vector_type(4))) unsigned int u32x4;

#define N_ROIS 512
#define FH 50
#define FW 50
#define KK1 25088      // 512*49
#define D1 4096

#define BM 512
#define BN 128
#define BK 32

// ---------------------------------------------------------------------------
// RoIPool: block = (roi, channel-group of 64). 4096 blocks (validated R5-R8).
// ---------------------------------------------------------------------------
__global__ __launch_bounds__(256) void roipool_kernel(
    const float* __restrict__ x, const float* __restrict__ rois,
    __bf16* __restrict__ pooled) {
  const int bid = blockIdx.x;
  const int roi = bid >> 3;
  const int cg = bid & 7;
  const float s = 0.0625f;
  const float r0 = rois[roi * 4 + 0], r1 = rois[roi * 4 + 1];
  const float r2 = rois[roi * 4 + 2], r3 = rois[roi * 4 + 3];
  int x1 = (int)(r0 * s); x1 = min(max(x1, 0), FW - 1);
  int y1 = (int)(r1 * s); y1 = min(max(y1, 0), FH - 1);
  int x2 = (int)(r2 * s); x2 = min(max(x2, 0), FW - 1);
  int y2 = (int)(r3 * s); y2 = min(max(y2, 0), FH - 1);
  const int ww = x2 - x1 + 1, hh = y2 - y1 + 1;
  __shared__ int cs[7], ce[7], rs[7], re[7];
  if (threadIdx.x < 7) {
    int i = threadIdx.x;
    cs[i] = x1 + (i * ww) / 7;
    ce[i] = x1 + ((i + 1) * ww + 6) / 7;
    rs[i] = y1 + (i * hh) / 7;
    re[i] = y1 + ((i + 1) * hh + 6) / 7;
  }
  __syncthreads();
  for (int idx = threadIdx.x; idx < 64 * 49; idx += 256) {
    int cl = idx / 49;
    int p = idx - cl * 49;
    int py = p / 7, px = p - py * 7;
    const int c = cg * 64 + cl;
    const float* base = x + (size_t)c * (FH * FW);
    float m = -3.402823466e38f;
    for (int y = rs[py]; y < re[py]; ++y) {
      const float* rowp = base + y * FW;
      for (int xx = cs[px]; xx < ce[px]; ++xx) m = fmaxf(m, rowp[xx]);
    }
    pooled[(size_t)roi * KK1 + c * 49 + p] = (__bf16)m;
  }
}

// ---------------------------------------------------------------------------
// GEMM: part[z][512][npad] = A[512,K](bf16) @ B[K,N](fp32 -> bf16 at stage)
// z = bid & ((1<<zshift)-1) (XCD-pins K-windows), n0 = (bid>>zshift)*128.
// Wave tile 64x128; acc[4][8]. A: 4 global_load_dwordx4 at iter top (L2-hot).
// B: 3 reg slots, LOAD_B(it+3)->slot[it%3]; after barrier WRITE_B tile it+1
// from slot[(it+1)%3] (2-iter issue->write slack). LDS Bu 2x8KB double-buffer,
// layout/swizzle R5/R7-validated. lgkmcnt(0)+s_barrier once/iter, no vmcnt(0).
// ---------------------------------------------------------------------------
template <typename OutT>
__global__ __launch_bounds__(512, 1) void gemm_kernel(
    const __bf16* __restrict__ A, const float* __restrict__ B,
    OutT* __restrict__ part, int N, int K, int kslice, int npad, int zshift) {
  __shared__ unsigned int Bu[2][2048];  // 2 x 8KB
  const int tid = threadIdx.x;
  const int lane = tid & 63;
  const int w = tid >> 6;
  const int bid = blockIdx.x;
  const int z = bid & ((1 << zshift) - 1);
  const int n0 = (bid >> zshift) * BN;
  const int kbeg = z * kslice;
  const int niters = kslice / BK;  // 98, 16, or 2
  const bool fullN = (n0 + BN) <= N;

  const int fr = lane & 15;
  const int ks = lane >> 4;

  f32x4 acc[4][8];
#pragma unroll
  for (int i = 0; i < 4; ++i)
#pragma unroll
    for (int j = 0; j < 8; ++j) acc[i][j] = (f32x4){0.f, 0.f, 0.f, 0.f};

  const int kmax = kbeg + kslice;

  // B staging: thread -> k-octet + single column (R7-validated)
  const int bc = tid & 127;       // column 0..127
  const int bkq = tid >> 7;       // k-octet 0..3
  const int bidx = bc * 16 + ((bkq ^ ((bc >> 2) & 3)) << 2);  // 16B aligned

  // static register state (rule #20)
  bf16x8 af0, af1, af2, af3;
  float bA0, bA1, bA2, bA3, bA4, bA5, bA6, bA7;
  float bB0, bB1, bB2, bB3, bB4, bB5, bB6, bB7;
  float bC0, bC1, bC2, bC3, bC4, bC5, bC6, bC7;

#define LOAD_A(t)                                                   \
  {                                                                 \
    const __bf16* ap =                                              \
        A + (size_t)(w * 64 + fr) * K + kbeg + (t) * BK + ks * 8;   \
    af0 = *(const bf16x8*)(ap);                                     \
    af1 = *(const bf16x8*)(ap + (size_t)16 * K);                    \
    af2 = *(const bf16x8*)(ap + (size_t)32 * K);                    \
    af3 = *(const bf16x8*)(ap + (size_t)48 * K);                    \
  }

#define LOAD_B(S, t)                                           \
  {                                                            \
    int kg = kbeg + (t) * BK;                                  \
    if (kg >= kmax) kg = kbeg; /* clamped dup, never used */   \
    const float* g0 = B + (size_t)(kg + 8 * bkq) * N;          \
    const int cc = n0 + bc;                                    \
    if (fullN) {                                               \
      S##0 = g0[cc];                S##1 = g0[(size_t)N + cc];     \
      S##2 = g0[(size_t)2 * N + cc]; S##3 = g0[(size_t)3 * N + cc];\
      S##4 = g0[(size_t)4 * N + cc]; S##5 = g0[(size_t)5 * N + cc];\
      S##6 = g0[(size_t)6 * N + cc]; S##7 = g0[(size_t)7 * N + cc];\
    } else {                                                   \
      const bool ok = cc < N;                                  \
      S##0 = ok ? g0[cc] : 0.f;                                \
      S##1 = ok ? g0[(size_t)N + cc] : 0.f;                    \
      S##2 = ok ? g0[(size_t)2 * N + cc] : 0.f;                \
      S##3 = ok ? g0[(size_t)3 * N + cc] : 0.f;                \
      S##4 = ok ? g0[(size_t)4 * N + cc] : 0.f;                \
      S##5 = ok ? g0[(size_t)5 * N + cc] : 0.f;                \
      S##6 = ok ? g0[(size_t)6 * N + cc] : 0.f;                \
      S##7 = ok ? g0[(size_t)7 * N + cc] : 0.f;                \
    }                                                          \
  }

#define WRITE_B(buf, S)                                        \
  {                                                            \
    union { __bf16 h[2]; unsigned int u; } q0, q1, q2, q3;     \
    q0.h[0] = (__bf16)S##0; q0.h[1] = (__bf16)S##1;            \
    q1.h[0] = (__bf16)S##2; q1.h[1] = (__bf16)S##3;            \
    q2.h[0] = (__bf16)S##4; q2.h[1] = (__bf16)S##5;            \
    q3.h[0] = (__bf16)S##6; q3.h[1] = (__bf16)S##7;            \
    *(u32x4*)&Bu[buf][bidx] = (u32x4){q0.u, q1.u, q2.u, q3.u}; \
  }

  // prologue: B tiles 0,1,2 in flight (slots A,B,C); tile 0 -> LDS buf 0
  LOAD_B(bA, 0);
  LOAD_B(bB, 1);
  LOAD_B(bC, 2);
  WRITE_B(0, bA);

  // iter it (requires it%3 == 0 at the bA call site):
  //   LOAD_A(it); LOAD_B(it+3)->slot[it%3]; lgkmcnt(0)+barrier;
  //   WRITE_B(tile it+1 from slot[(it+1)%3]); MFMA on Bu[it&1].
#define BODY(it, ldB, wrB)                                            \
  {                                                                   \
    LOAD_A(it);                                                       \
    LOAD_B(ldB, (it) + 3);                                            \
    asm volatile("s_waitcnt lgkmcnt(0)" ::: "memory");                \
    __builtin_amdgcn_s_barrier();                                     \
    __builtin_amdgcn_sched_barrier(0);                                \
    if ((it) + 1 < niters) WRITE_B(((it) + 1) & 1, wrB);              \
    _Pragma("unroll")                                                 \
    for (int nf = 0; nf < 8; ++nf) {                                  \
      const int c = nf * 16 + fr;                                     \
      const int slot = ks ^ ((c >> 2) & 3);                           \
      bf16x8 bfr = *(const bf16x8*)((const char*)&Bu[(it) & 1][0] +   \
                                    c * 64 + slot * 16);              \
      acc[0][nf] = __builtin_amdgcn_mfma_f32_16x16x32_bf16(af0, bfr, acc[0][nf], 0, 0, 0); \
      acc[1][nf] = __builtin_amdgcn_mfma_f32_16x16x32_bf16(af1, bfr, acc[1][nf], 0, 0, 0); \
      acc[2][nf] = __builtin_amdgcn_mfma_f32_16x16x32_bf16(af2, bfr, acc[2][nf], 0, 0, 0); \
      acc[3][nf] = __builtin_amdgcn_mfma_f32_16x16x32_bf16(af3, bfr, acc[3][nf], 0, 0, 0); \
    }                                                                 \
  }

  int it = 0;
  for (; it + 2 < niters; it += 3) {
    BODY(it + 0, bA, bB);
    BODY(it + 1, bB, bC);
    BODY(it + 2, bC, bA);
  }
  // tail: it is always ≡ 0 (mod 3) here; handles niters%3 ∈ {1,2}
  if (it < niters)     BODY(it + 0, bA, bB);
  if (it + 1 < niters) BODY(it + 1, bB, bC);
#undef BODY
#undef WRITE_B
#undef LOAD_B
#undef LOAD_A

  // epilogue: C/D layout col = lane&15, row = (lane>>4)*4 + r
  const int r0 = ks * 4;
  OutT* pbase = part + (size_t)z * 512 * npad;
#pragma unroll
  for (int mf = 0; mf < 4; ++mf)
#pragma unroll
    for (int nf = 0; nf < 8; ++nf) {
      const int col = n0 + nf * 16 + fr;
#pragma unroll
      for (int r = 0; r < 4; ++r) {
        const int row = w * 64 + mf * 16 + r0 + r;
        pbase[(size_t)row * npad + col] = (OutT)acc[mf][nf][r];
      }
    }
}

// sum bf16 split-K partials + bias, relu -> bf16 activations [512][4096]
__global__ __launch_bounds__(256) void reduce_relu_kernel(
    const __bf16* __restrict__ part, const float* __restrict__ bias,
    __bf16* __restrict__ out, int nsplit) {
  const int idx = blockIdx.x * 256 + threadIdx.x;
  const int flat = idx * 8;
  if (flat >= 512 * 4096) return;
  float s[8];
#pragma unroll
  for (int j = 0; j < 8; ++j) s[j] = 0.f;
  for (int sp = 0; sp < nsplit; ++sp) {
    bf16x8 v = *(const bf16x8*)(part + (size_t)sp * (512 * 4096) + flat);
#pragma unroll
    for (int j = 0; j < 8; ++j) s[j] += (float)v[j];
  }
  const int nb = flat & 4095;
  bf16x8 o;
#pragma unroll
  for (int j = 0; j < 8; ++j) {
    float v = s[j] + bias[nb + j];
    o[j] = (__bf16)(v > 0.f ? v : 0.f);
  }
  *(bf16x8*)(out + flat) = o;
}

// final: sum split-K fp32 partials (stride 128) + bias -> d_out fp32
__global__ __launch_bounds__(256) void reduce_out_kernel(
    const float* __restrict__ pc, const float* __restrict__ pr,
    const float* __restrict__ bcls, const float* __restrict__ breg,
    float* __restrict__ out, int nsplit) {
  const int gid = blockIdx.x * 256 + threadIdx.x;
  if (gid >= 512 * 105) return;
  if (gid < 512 * 21) {
    const int m = gid / 21, j = gid - m * 21;
    float s = bcls[j];
    for (int sp = 0; sp < nsplit; ++sp)
      s += pc[(size_t)sp * 512 * 128 + m * 128 + j];
    out[gid] = s;
  } else {
    const int g = gid - 512 * 21;
    const int m = g / 84, j = g - m * 84;
    float s = breg[j];
    for (int sp = 0; sp < nsplit; ++sp)
      s += pr[(size_t)sp * 512 * 128 + m * 128 + j];
    out[gid] = s;
  }
}

extern "C" void kernel_launch(void* const* d_in, const int* in_sizes, int n_in,
                              void* d_out, int out_size, void* d_ws, size_t ws_size,
                              hipStream_t stream) {
  (void)in_sizes; (void)n_in; (void)out_size;
  const float* x    = (const float*)d_in[0];
  const float* rois = (const float*)d_in[2];
  const float* W1   = (const float*)d_in[3];
  const float* b1   = (const float*)d_in[4];
  const float* W2   = (const float*)d_in[5];
  const float* b2   = (const float*)d_in[6];
  const float* Wcls = (const float*)d_in[7];
  const float* bcls = (const float*)d_in[8];
  const float* Wreg = (const float*)d_in[9];
  const float* breg = (const float*)d_in[10];
  float* out = (float*)d_out;

  const size_t pooled_b = (size_t)512 * KK1 * 2;        // 25,690,112
  const size_t act_b = (size_t)512 * D1 * 2;            // 4 MiB
  const size_t need8 = pooled_b + (size_t)8 * act_b + 2 * act_b;
  const int ns = (ws_size >= need8) ? 8 : 2;            // ws ~1.6GB: ns=8
  const int zshift = (ns == 8) ? 3 : 1;

  char* ws = (char*)d_ws;
  __bf16* pooled = (__bf16*)ws;
  __bf16* part1 = (__bf16*)(ws + pooled_b);             // ns * 4MiB
  __bf16* f1 = (__bf16*)(ws + pooled_b + (size_t)ns * act_b);
  __bf16* f2 = (__bf16*)(ws + pooled_b + (size_t)ns * act_b + act_b);
  __bf16* part2 = (__bf16*)ws;                          // alias dead pooled+part1
  float* pcls = (float*)ws;                             // heads phase aliases
  float* preg = (float*)(ws + (size_t)64 * 512 * 128 * 4);  // +16.8MB

  // 1) RoIPool -> pooled bf16 [512, 25088]; 4096 blocks for occupancy
  roipool_kernel<<<N_ROIS * 8, 256, 0, stream>>>(x, rois, pooled);

  // 2) GEMM1: pooled @ W1[25088,4096]; W1 read exactly once; z-pinned XCDs
  gemm_kernel<__bf16><<<32 * ns, 512, 0, stream>>>(
      pooled, W1, part1, 4096, KK1, KK1 / ns, 4096, zshift);
  reduce_relu_kernel<<<1024, 256, 0, stream>>>(part1, b1, f1, ns);

  // 3) GEMM2: f1 @ W2[4096,4096]
  gemm_kernel<__bf16><<<32 * ns, 512, 0, stream>>>(
      f1, W2, part2, 4096, 4096, 4096 / ns, 4096, zshift);
  reduce_relu_kernel<<<1024, 256, 0, stream>>>(part2, b2, f2, ns);

  // 4) heads: single n-tile each (21,84 <= 128), split-K=64, npad=128
  gemm_kernel<float><<<64, 512, 0, stream>>>(
      f2, Wcls, pcls, 21, 4096, 64, 128, 6);
  gemm_kernel<float><<<64, 512, 0, stream>>>(
      f2, Wreg, preg, 84, 4096, 64, 128, 6);
  reduce_out_kernel<<<(512 * 105 + 255) / 256, 256, 0, stream>>>(
      pcls, preg, bcls, breg, out, 64);
}